// Round 1
// baseline (1783.073 us; speedup 1.0000x reference)
//
#include <hip/hip_runtime.h>
#include <math.h>

// Problem constants (from reference)
#define NB   512    // batch
#define NQ   64     // queries
#define NCC  1000   // candidates
#define EE   128    // embed
#define HH   8      // heads
#define HDD  16     // head dim
#define NL   3      // GAT layers
#define DD   4      // cluster depth
#define PP   130    // LDS pitch (even -> 8B-aligned rows, bank-spread)

// ---------------------------------------------------------------------------
// Kernel 1: 3 fused MHA layers + final query projection. One block per batch.
// x stays in LDS the whole time. Buffers: Xs (residual stream), As (Q -> o),
// Bs (K -> V).  LDS = 3 * 64*130*4 = 99,840 B.
// ---------------------------------------------------------------------------
__global__ __launch_bounds__(512, 1) void gat_query_kernel(
    const float* __restrict__ hin,
    const float* __restrict__ gWq, const float* __restrict__ gbq,
    const float* __restrict__ gWk, const float* __restrict__ gbk,
    const float* __restrict__ gWv, const float* __restrict__ gbv,
    const float* __restrict__ gWo, const float* __restrict__ gbo,
    const float* __restrict__ Wq,  const float* __restrict__ bq,
    float* __restrict__ query)
{
  __shared__ float Xs[NQ * PP];
  __shared__ float As[NQ * PP];
  __shared__ float Bs[NQ * PP];
  const int b   = blockIdx.x;
  const int tid = threadIdx.x;

  // load x (coalesced)
  for (int idx = tid; idx < NQ * EE; idx += 512)
    Xs[(idx >> 7) * PP + (idx & 127)] = hin[(size_t)b * NQ * EE + idx];
  __syncthreads();

  for (int l = 0; l < NL; ++l) {
    const float* Wql = gWq + l * EE * EE;  const float* bql = gbq + l * EE;
    const float* Wkl = gWk + l * EE * EE;  const float* bkl = gbk + l * EE;
    const float* Wvl = gWv + l * EE * EE;  const float* bvl = gbv + l * EE;
    const float* Wol = gWo + l * EE * EE;  const float* bol = gbo + l * EE;

    // ---- Phase 1: Q -> As, K -> Bs.  512 threads = 2 mats x 64 colpairs x 4 rowquarts
    {
      const int mat = tid >> 8;          // 0: Q, 1: K
      const int rem = tid & 255;
      const int cg  = rem & 63;          // columns 2cg, 2cg+1
      const int rq  = rem >> 6;          // rows 16rq .. 16rq+15
      const float* W    = mat ? Wkl : Wql;
      const float* bias = mat ? bkl : bql;
      float* dst        = mat ? Bs : As;
      const int e0 = cg * 2, r0 = rq * 16;
      float acc0[16], acc1[16];
      #pragma unroll
      for (int n = 0; n < 16; ++n) { acc0[n] = 0.f; acc1[n] = 0.f; }
      for (int k = 0; k < EE; k += 2) {
        const float2 wa = *(const float2*)&W[k * EE + e0];
        const float2 wb = *(const float2*)&W[(k + 1) * EE + e0];
        #pragma unroll
        for (int n = 0; n < 16; ++n) {
          const float2 xv = *(const float2*)&Xs[(r0 + n) * PP + k];
          acc0[n] += xv.x * wa.x + xv.y * wb.x;
          acc1[n] += xv.x * wa.y + xv.y * wb.y;
        }
      }
      const float b0 = bias[e0], b1 = bias[e0 + 1];
      #pragma unroll
      for (int n = 0; n < 16; ++n) {
        dst[(r0 + n) * PP + e0]     = acc0[n] + b0;
        dst[(r0 + n) * PP + e0 + 1] = acc1[n] + b1;
      }
    }
    __syncthreads();

    // ---- Phase 2: scores + softmax. 512 threads = 8 heads x 64 query rows.
    const int hh = tid >> 6;
    const int qi = tid & 63;
    float s[NQ];
    {
      float qv[HDD];
      #pragma unroll
      for (int d = 0; d < HDD; ++d) qv[d] = As[qi * PP + hh * HDD + d];
      #pragma unroll
      for (int j = 0; j < NQ; ++j) {
        float acc = 0.f;
        #pragma unroll
        for (int d = 0; d < HDD; d += 2) {
          const float2 kv = *(const float2*)&Bs[j * PP + hh * HDD + d];
          acc += qv[d] * kv.x + qv[d + 1] * kv.y;
        }
        s[j] = acc * 0.25f;   // 1/sqrt(HD)
      }
      float m = s[0];
      #pragma unroll
      for (int j = 1; j < NQ; ++j) m = fmaxf(m, s[j]);
      float sum = 0.f;
      #pragma unroll
      for (int j = 0; j < NQ; ++j) { s[j] = expf(s[j] - m); sum += s[j]; }
      const float inv = 1.f / sum;
      #pragma unroll
      for (int j = 0; j < NQ; ++j) s[j] *= inv;
    }
    __syncthreads();   // done reading As(Q)/Bs(K)

    // ---- Phase 3: V -> Bs (overwrites K). 512 threads = 128 cols x 4 rowquarts
    {
      const int e  = tid & 127;
      const int rq = tid >> 7;
      const int r0 = rq * 16;
      float acc[16];
      #pragma unroll
      for (int n = 0; n < 16; ++n) acc[n] = 0.f;
      for (int k = 0; k < EE; k += 2) {
        const float w0 = Wvl[k * EE + e];
        const float w1 = Wvl[(k + 1) * EE + e];
        #pragma unroll
        for (int n = 0; n < 16; ++n) {
          const float2 xv = *(const float2*)&Xs[(r0 + n) * PP + k];
          acc[n] += xv.x * w0 + xv.y * w1;
        }
      }
      const float bb = bvl[e];
      #pragma unroll
      for (int n = 0; n < 16; ++n) Bs[(r0 + n) * PP + e] = acc[n] + bb;
    }
    __syncthreads();

    // ---- Phase 4: o = att @ V -> As (overwrites Q)
    {
      float o[HDD];
      #pragma unroll
      for (int d = 0; d < HDD; ++d) o[d] = 0.f;
      #pragma unroll
      for (int j = 0; j < NQ; ++j) {
        const float a = s[j];
        #pragma unroll
        for (int d = 0; d < HDD; d += 2) {
          const float2 vv = *(const float2*)&Bs[j * PP + hh * HDD + d];
          o[d]     += a * vv.x;
          o[d + 1] += a * vv.y;
        }
      }
      #pragma unroll
      for (int d = 0; d < HDD; ++d) As[qi * PP + hh * HDD + d] = o[d];
    }
    __syncthreads();

    // ---- Phase 5: X += o @ Wo + bo
    {
      const int e  = tid & 127;
      const int rq = tid >> 7;
      const int r0 = rq * 16;
      float acc[16];
      #pragma unroll
      for (int n = 0; n < 16; ++n) acc[n] = 0.f;
      for (int f = 0; f < EE; f += 2) {
        const float w0 = Wol[f * EE + e];
        const float w1 = Wol[(f + 1) * EE + e];
        #pragma unroll
        for (int n = 0; n < 16; ++n) {
          const float2 ov = *(const float2*)&As[(r0 + n) * PP + f];
          acc[n] += ov.x * w0 + ov.y * w1;
        }
      }
      const float bb = bol[e];
      #pragma unroll
      for (int n = 0; n < 16; ++n) Xs[(r0 + n) * PP + e] += acc[n] + bb;
    }
    __syncthreads();
  }

  // ---- Final query projection: query = X @ Wq + bq
  {
    const int e  = tid & 127;
    const int rq = tid >> 7;
    const int r0 = rq * 16;
    float acc[16];
    #pragma unroll
    for (int n = 0; n < 16; ++n) acc[n] = 0.f;
    for (int k = 0; k < EE; k += 2) {
      const float w0 = Wq[k * EE + e];
      const float w1 = Wq[(k + 1) * EE + e];
      #pragma unroll
      for (int n = 0; n < 16; ++n) {
        const float2 xv = *(const float2*)&Xs[(r0 + n) * PP + k];
        acc[n] += xv.x * w0 + xv.y * w1;
      }
    }
    const float bb = bq[e];
    #pragma unroll
    for (int n = 0; n < 16; ++n)
      query[(size_t)b * NQ * EE + (r0 + n) * EE + e] = acc[n] + bb;
  }
}

// ---------------------------------------------------------------------------
// Kernel 2: fused key-projection + compat + mean + argmax. One block per batch,
// 16 chunks of 64 candidates. LDS ~= 106 KB.
// out[0..NB) = action (as float), out+NB = compat (B,NQ,NC).
// ---------------------------------------------------------------------------
__global__ __launch_bounds__(256, 1) void compat_kernel(
    const float* __restrict__ cin,
    const float* __restrict__ query,
    const unsigned char* __restrict__ mask,      // (B, NQ, NC+1), bool
    const unsigned char* __restrict__ clusters,  // (B, D, NC), bool
    const int* __restrict__ depot_id,
    const float* __restrict__ Wk, const float* __restrict__ bk,
    float* __restrict__ out)
{
  __shared__ float Qs[NQ * PP];
  __shared__ float Cs[64 * PP];
  __shared__ float Ks[64 * PP];
  __shared__ float colsum[1024];
  __shared__ float redv[256];
  __shared__ int   redi[256];
  const int b   = blockIdx.x;
  const int tid = threadIdx.x;
  float* compat_out = out + NB;

  for (int idx = tid; idx < NQ * EE; idx += 256)
    Qs[(idx >> 7) * PP + (idx & 127)] = query[(size_t)b * NQ * EE + idx];
  for (int j = tid; j < 1024; j += 256) colsum[j] = 0.f;
  __syncthreads();

  for (int ch = 0; ch < 16; ++ch) {
    const int j0 = ch * 64;
    // stage c chunk (float4, coalesced); pad OOB rows with zeros
    for (int idx = tid; idx < 64 * EE / 4; idx += 256) {
      const int j  = idx >> 5;            // 32 float4 per row
      const int k4 = (idx & 31) * 4;
      float4 v = make_float4(0.f, 0.f, 0.f, 0.f);
      if (j0 + j < NCC)
        v = *(const float4*)&cin[((size_t)b * NCC + j0 + j) * EE + k4];
      Cs[j * PP + k4 + 0] = v.x; Cs[j * PP + k4 + 1] = v.y;
      Cs[j * PP + k4 + 2] = v.z; Cs[j * PP + k4 + 3] = v.w;
    }
    __syncthreads();

    // key = Cs @ Wk + bk -> Ks.  256 threads = 64 colpairs x 4 rowquarts
    {
      const int cg = tid & 63;
      const int rh = tid >> 6;
      const int e0 = cg * 2, r0 = rh * 16;
      float acc0[16], acc1[16];
      #pragma unroll
      for (int n = 0; n < 16; ++n) { acc0[n] = 0.f; acc1[n] = 0.f; }
      for (int k = 0; k < EE; k += 2) {
        const float2 wa = *(const float2*)&Wk[k * EE + e0];
        const float2 wb = *(const float2*)&Wk[(k + 1) * EE + e0];
        #pragma unroll
        for (int n = 0; n < 16; ++n) {
          const float2 cv = *(const float2*)&Cs[(r0 + n) * PP + k];
          acc0[n] += cv.x * wa.x + cv.y * wb.x;
          acc1[n] += cv.x * wa.y + cv.y * wb.y;
        }
      }
      const float b0 = bk[e0], b1 = bk[e0 + 1];
      #pragma unroll
      for (int n = 0; n < 16; ++n) {
        Ks[(r0 + n) * PP + e0]     = acc0[n] + b0;
        Ks[(r0 + n) * PP + e0 + 1] = acc1[n] + b1;
      }
    }
    __syncthreads();

    // compat tile: 64 queries x 64 candidates, 4x4 per thread
    {
      const int tx = tid & 15;   // candidate group (4 j's)
      const int ty = tid >> 4;   // query group (4 qi's)
      float acc[4][4];
      #pragma unroll
      for (int i = 0; i < 4; ++i)
        #pragma unroll
        for (int j = 0; j < 4; ++j) acc[i][j] = 0.f;
      for (int k = 0; k < EE; k += 2) {
        float2 qf[4], kf[4];
        #pragma unroll
        for (int i = 0; i < 4; ++i) qf[i] = *(const float2*)&Qs[(ty * 4 + i) * PP + k];
        #pragma unroll
        for (int j = 0; j < 4; ++j) kf[j] = *(const float2*)&Ks[(tx * 4 + j) * PP + k];
        #pragma unroll
        for (int i = 0; i < 4; ++i)
          #pragma unroll
          for (int j = 0; j < 4; ++j)
            acc[i][j] += qf[i].x * kf[j].x + qf[i].y * kf[j].y;
      }
      const int jbase = j0 + tx * 4;
      if (jbase < NCC) {   // NC multiple of 4: tile fully valid or fully OOB
        float jsum[4] = {0.f, 0.f, 0.f, 0.f};
        #pragma unroll
        for (int i = 0; i < 4; ++i) {
          const int q_i = ty * 4 + i;
          const unsigned char* mrow =
              mask + ((size_t)b * NQ + q_i) * (NCC + 1) + 1;
          float4 vv;
          vv.x = mrow[jbase + 0] ? -INFINITY : tanhf(acc[i][0] * 0.25f) * 10.f;
          vv.y = mrow[jbase + 1] ? -INFINITY : tanhf(acc[i][1] * 0.25f) * 10.f;
          vv.z = mrow[jbase + 2] ? -INFINITY : tanhf(acc[i][2] * 0.25f) * 10.f;
          vv.w = mrow[jbase + 3] ? -INFINITY : tanhf(acc[i][3] * 0.25f) * 10.f;
          *(float4*)&compat_out[((size_t)b * NQ + q_i) * NCC + jbase] = vv;
          jsum[0] += vv.x; jsum[1] += vv.y; jsum[2] += vv.z; jsum[3] += vv.w;
        }
        #pragma unroll
        for (int j = 0; j < 4; ++j) atomicAdd(&colsum[jbase + j], jsum[j]);
      }
    }
    __syncthreads();
  }

  // compts = colsum/NQ, cluster mask, first-occurrence argmax
  const int dep = depot_id[0];
  float bestv = -INFINITY;
  int   besti = 0x7fffffff;
  for (int j = tid; j < NCC; j += 256) {
    float t = colsum[j] * (1.0f / (float)NQ);
    if (clusters[((size_t)b * DD + dep) * NCC + j]) t = -INFINITY;
    if (t > bestv || (t == bestv && j < besti)) { bestv = t; besti = j; }
  }
  redv[tid] = bestv; redi[tid] = besti;
  __syncthreads();
  if (tid == 0) {
    float bv = redv[0]; int bi = redi[0];
    for (int t = 1; t < 256; ++t) {
      if (redv[t] > bv || (redv[t] == bv && redi[t] < bi)) {
        bv = redv[t]; bi = redi[t];
      }
    }
    out[b] = (float)bi;
  }
}

// ---------------------------------------------------------------------------
extern "C" void kernel_launch(void* const* d_in, const int* in_sizes, int n_in,
                              void* d_out, int out_size, void* d_ws, size_t ws_size,
                              hipStream_t stream) {
  const float* hin      = (const float*)d_in[0];
  const float* cin      = (const float*)d_in[1];
  const unsigned char* mask     = (const unsigned char*)d_in[2];
  const unsigned char* clusters = (const unsigned char*)d_in[3];
  const int*   depot    = (const int*)d_in[4];
  const float* gWq = (const float*)d_in[5];
  const float* gbq = (const float*)d_in[6];
  const float* gWk = (const float*)d_in[7];
  const float* gbk = (const float*)d_in[8];
  const float* gWv = (const float*)d_in[9];
  const float* gbv = (const float*)d_in[10];
  const float* gWo = (const float*)d_in[11];
  const float* gbo = (const float*)d_in[12];
  const float* Wq  = (const float*)d_in[13];
  const float* bq  = (const float*)d_in[14];
  const float* Wk  = (const float*)d_in[15];
  const float* bk  = (const float*)d_in[16];
  float* out   = (float*)d_out;
  float* query = (float*)d_ws;   // 512*64*128 floats = 16 MB scratch

  gat_query_kernel<<<NB, 512, 0, stream>>>(hin, gWq, gbq, gWk, gbk, gWv, gbv,
                                           gWo, gbo, Wq, bq, query);
  compat_kernel<<<NB, 256, 0, stream>>>(cin, query, mask, clusters, depot,
                                        Wk, bk, out);
}

// Round 2
// 1153.049 us; speedup vs baseline: 1.5464x; 1.5464x over previous
//
#include <hip/hip_runtime.h>
#include <math.h>

// Problem constants (from reference)
#define NB   512    // batch
#define NQ   64     // queries
#define NCC  1000   // candidates
#define EE   128    // embed
#define HH   8      // heads
#define HDD  16     // head dim
#define NL   3      // GAT layers
#define DD   4      // cluster depth
#define PP   130    // LDS pitch for fp32 kernel
#define KP   136    // LDS pitch (ushort elems) for K hi/lo staging; 272B rows, 16B-aligned

typedef __bf16 bf16x8 __attribute__((ext_vector_type(8)));
typedef unsigned short u16x8 __attribute__((ext_vector_type(8)));
typedef float f32x4 __attribute__((ext_vector_type(4)));

__device__ __forceinline__ unsigned short f2bf(float x) {
  union { float f; unsigned u; } v; v.f = x;
  unsigned r = (v.u + 0x7fffu + ((v.u >> 16) & 1u)) >> 16;
  return (unsigned short)r;
}
__device__ __forceinline__ float bf2f(unsigned short h) {
  union { unsigned u; float f; } v; v.u = ((unsigned)h) << 16;
  return v.f;
}

// ---------------------------------------------------------------------------
// Kernel 1: 3 fused MHA layers + final query projection. One block per batch.
// (unchanged from R1 — target of a later round)
// ---------------------------------------------------------------------------
__global__ __launch_bounds__(512, 1) void gat_query_kernel(
    const float* __restrict__ hin,
    const float* __restrict__ gWq, const float* __restrict__ gbq,
    const float* __restrict__ gWk, const float* __restrict__ gbk,
    const float* __restrict__ gWv, const float* __restrict__ gbv,
    const float* __restrict__ gWo, const float* __restrict__ gbo,
    const float* __restrict__ Wq,  const float* __restrict__ bq,
    float* __restrict__ query)
{
  __shared__ float Xs[NQ * PP];
  __shared__ float As[NQ * PP];
  __shared__ float Bs[NQ * PP];
  const int b   = blockIdx.x;
  const int tid = threadIdx.x;

  for (int idx = tid; idx < NQ * EE; idx += 512)
    Xs[(idx >> 7) * PP + (idx & 127)] = hin[(size_t)b * NQ * EE + idx];
  __syncthreads();

  for (int l = 0; l < NL; ++l) {
    const float* Wql = gWq + l * EE * EE;  const float* bql = gbq + l * EE;
    const float* Wkl = gWk + l * EE * EE;  const float* bkl = gbk + l * EE;
    const float* Wvl = gWv + l * EE * EE;  const float* bvl = gbv + l * EE;
    const float* Wol = gWo + l * EE * EE;  const float* bol = gbo + l * EE;

    {
      const int mat = tid >> 8;
      const int rem = tid & 255;
      const int cg  = rem & 63;
      const int rq  = rem >> 6;
      const float* W    = mat ? Wkl : Wql;
      const float* bias = mat ? bkl : bql;
      float* dst        = mat ? Bs : As;
      const int e0 = cg * 2, r0 = rq * 16;
      float acc0[16], acc1[16];
      #pragma unroll
      for (int n = 0; n < 16; ++n) { acc0[n] = 0.f; acc1[n] = 0.f; }
      for (int k = 0; k < EE; k += 2) {
        const float2 wa = *(const float2*)&W[k * EE + e0];
        const float2 wb = *(const float2*)&W[(k + 1) * EE + e0];
        #pragma unroll
        for (int n = 0; n < 16; ++n) {
          const float2 xv = *(const float2*)&Xs[(r0 + n) * PP + k];
          acc0[n] += xv.x * wa.x + xv.y * wb.x;
          acc1[n] += xv.x * wa.y + xv.y * wb.y;
        }
      }
      const float b0 = bias[e0], b1 = bias[e0 + 1];
      #pragma unroll
      for (int n = 0; n < 16; ++n) {
        dst[(r0 + n) * PP + e0]     = acc0[n] + b0;
        dst[(r0 + n) * PP + e0 + 1] = acc1[n] + b1;
      }
    }
    __syncthreads();

    const int hh = tid >> 6;
    const int qi = tid & 63;
    float s[NQ];
    {
      float qv[HDD];
      #pragma unroll
      for (int d = 0; d < HDD; ++d) qv[d] = As[qi * PP + hh * HDD + d];
      #pragma unroll
      for (int j = 0; j < NQ; ++j) {
        float acc = 0.f;
        #pragma unroll
        for (int d = 0; d < HDD; d += 2) {
          const float2 kv = *(const float2*)&Bs[j * PP + hh * HDD + d];
          acc += qv[d] * kv.x + qv[d + 1] * kv.y;
        }
        s[j] = acc * 0.25f;
      }
      float m = s[0];
      #pragma unroll
      for (int j = 1; j < NQ; ++j) m = fmaxf(m, s[j]);
      float sum = 0.f;
      #pragma unroll
      for (int j = 0; j < NQ; ++j) { s[j] = expf(s[j] - m); sum += s[j]; }
      const float inv = 1.f / sum;
      #pragma unroll
      for (int j = 0; j < NQ; ++j) s[j] *= inv;
    }
    __syncthreads();

    {
      const int e  = tid & 127;
      const int rq = tid >> 7;
      const int r0 = rq * 16;
      float acc[16];
      #pragma unroll
      for (int n = 0; n < 16; ++n) acc[n] = 0.f;
      for (int k = 0; k < EE; k += 2) {
        const float w0 = Wvl[k * EE + e];
        const float w1 = Wvl[(k + 1) * EE + e];
        #pragma unroll
        for (int n = 0; n < 16; ++n) {
          const float2 xv = *(const float2*)&Xs[(r0 + n) * PP + k];
          acc[n] += xv.x * w0 + xv.y * w1;
        }
      }
      const float bb = bvl[e];
      #pragma unroll
      for (int n = 0; n < 16; ++n) Bs[(r0 + n) * PP + e] = acc[n] + bb;
    }
    __syncthreads();

    {
      float o[HDD];
      #pragma unroll
      for (int d = 0; d < HDD; ++d) o[d] = 0.f;
      #pragma unroll
      for (int j = 0; j < NQ; ++j) {
        const float a = s[j];
        #pragma unroll
        for (int d = 0; d < HDD; d += 2) {
          const float2 vv = *(const float2*)&Bs[j * PP + hh * HDD + d];
          o[d]     += a * vv.x;
          o[d + 1] += a * vv.y;
        }
      }
      #pragma unroll
      for (int d = 0; d < HDD; ++d) As[qi * PP + hh * HDD + d] = o[d];
    }
    __syncthreads();

    {
      const int e  = tid & 127;
      const int rq = tid >> 7;
      const int r0 = rq * 16;
      float acc[16];
      #pragma unroll
      for (int n = 0; n < 16; ++n) acc[n] = 0.f;
      for (int f = 0; f < EE; f += 2) {
        const float w0 = Wol[f * EE + e];
        const float w1 = Wol[(f + 1) * EE + e];
        #pragma unroll
        for (int n = 0; n < 16; ++n) {
          const float2 ov = *(const float2*)&As[(r0 + n) * PP + f];
          acc[n] += ov.x * w0 + ov.y * w1;
        }
      }
      const float bb = bol[e];
      #pragma unroll
      for (int n = 0; n < 16; ++n) Xs[(r0 + n) * PP + e] += acc[n] + bb;
    }
    __syncthreads();
  }

  {
    const int e  = tid & 127;
    const int rq = tid >> 7;
    const int r0 = rq * 16;
    float acc[16];
    #pragma unroll
    for (int n = 0; n < 16; ++n) acc[n] = 0.f;
    for (int k = 0; k < EE; k += 2) {
      const float w0 = Wq[k * EE + e];
      const float w1 = Wq[(k + 1) * EE + e];
      #pragma unroll
      for (int n = 0; n < 16; ++n) {
        const float2 xv = *(const float2*)&Xs[(r0 + n) * PP + k];
        acc[n] += xv.x * w0 + xv.y * w1;
      }
    }
    const float bb = bq[e];
    #pragma unroll
    for (int n = 0; n < 16; ++n)
      query[(size_t)b * NQ * EE + (r0 + n) * EE + e] = acc[n] + bb;
  }
}

// ---------------------------------------------------------------------------
// Kernel 1b: Wk -> Wk^T split into bf16 hi/lo (runs every launch; tiny).
// Wkt layout: [n][k] so MFMA B-fragments read 8 contiguous k's.
// ---------------------------------------------------------------------------
__global__ void wkt_kernel(const float* __restrict__ Wk,
                           unsigned short* __restrict__ wkt_hi,
                           unsigned short* __restrict__ wkt_lo)
{
  const int idx = blockIdx.x * 256 + threadIdx.x;   // 64 blocks x 256 = 16384
  const int k = idx >> 7, n = idx & 127;
  const float v = Wk[idx];
  const unsigned short hi = f2bf(v);
  const unsigned short lo = f2bf(v - bf2f(hi));
  wkt_hi[n * EE + k] = hi;
  wkt_lo[n * EE + k] = lo;
}

// ---------------------------------------------------------------------------
// Kernel 2: MFMA compat. One block per (candidate-chunk, batch).
// Phase A: K_chunk(128x128) = C_chunk @ Wk + bk via bf16 hi/lo split MFMA
//          (Ah*Bh + Ah*Bl + Al*Bh ~ fp32), result -> LDS as bf16 hi/lo.
// Phase B: S(64x128) = Q @ K_chunk^T, same split; tanh*10, mask, store compat,
//          column sums -> compts (ws).
// LDS: 2 * 128*136*2B = 69.6 KB -> 2 blocks/CU.
// ---------------------------------------------------------------------------
__global__ __launch_bounds__(256, 2) void compat_mfma_kernel(
    const float* __restrict__ cin,
    const float* __restrict__ query,
    const unsigned char* __restrict__ mask,
    const unsigned short* __restrict__ wkt_hi,
    const unsigned short* __restrict__ wkt_lo,
    const float* __restrict__ bk,
    float* __restrict__ compat_out,
    float* __restrict__ compts)
{
  __shared__ unsigned short Khi[128 * KP];
  __shared__ unsigned short Klo[128 * KP];
  __shared__ float colsum[128];

  const int ch   = blockIdx.x;          // 0..7 candidate chunk (128 cands)
  const int b    = blockIdx.y;          // batch
  const int tid  = threadIdx.x;
  const int wave = tid >> 6;
  const int lane = tid & 63;
  const int l15  = lane & 15;
  const int quad = lane >> 4;

  if (tid < 128) colsum[tid] = 0.f;

  // ---------------- Phase A: key projection ----------------
  {
    f32x4 acc[2][8];
    #pragma unroll
    for (int mt = 0; mt < 2; ++mt)
      #pragma unroll
      for (int nt = 0; nt < 8; ++nt)
        acc[mt][nt] = (f32x4){0.f, 0.f, 0.f, 0.f};

    #pragma unroll
    for (int k4 = 0; k4 < 4; ++k4) {
      const int k0 = k4 * 32 + quad * 8;
      // A-fragments: C rows (hi/lo split), direct from global
      bf16x8 ahi[2], alo[2];
      #pragma unroll
      for (int mt = 0; mt < 2; ++mt) {
        int grow = ch * 128 + (wave * 2 + mt) * 16 + l15;
        if (grow > NCC - 1) grow = NCC - 1;     // tail clamp (values unused)
        const float* src = &cin[((size_t)b * NCC + grow) * EE + k0];
        const float4 x0 = *(const float4*)&src[0];
        const float4 x1 = *(const float4*)&src[4];
        float xv[8] = {x0.x, x0.y, x0.z, x0.w, x1.x, x1.y, x1.z, x1.w};
        u16x8 h, l;
        #pragma unroll
        for (int j = 0; j < 8; ++j) {
          unsigned short hb = f2bf(xv[j]);
          h[j] = hb;
          l[j] = f2bf(xv[j] - bf2f(hb));
        }
        ahi[mt] = __builtin_bit_cast(bf16x8, h);
        alo[mt] = __builtin_bit_cast(bf16x8, l);
      }
      // B-fragments: Wk^T hi/lo, contiguous 16B loads (L1/L2-hot)
      #pragma unroll
      for (int nt = 0; nt < 8; ++nt) {
        const int n = nt * 16 + l15;
        const bf16x8 bhi = __builtin_bit_cast(bf16x8, *(const u16x8*)&wkt_hi[n * EE + k0]);
        const bf16x8 blo = __builtin_bit_cast(bf16x8, *(const u16x8*)&wkt_lo[n * EE + k0]);
        #pragma unroll
        for (int mt = 0; mt < 2; ++mt) {
          acc[mt][nt] = __builtin_amdgcn_mfma_f32_16x16x32_bf16(ahi[mt], bhi, acc[mt][nt], 0, 0, 0);
          acc[mt][nt] = __builtin_amdgcn_mfma_f32_16x16x32_bf16(ahi[mt], blo, acc[mt][nt], 0, 0, 0);
          acc[mt][nt] = __builtin_amdgcn_mfma_f32_16x16x32_bf16(alo[mt], bhi, acc[mt][nt], 0, 0, 0);
        }
      }
    }

    // bias + split to bf16 hi/lo -> LDS  (D layout: col=lane&15, row=quad*4+r)
    #pragma unroll
    for (int nt = 0; nt < 8; ++nt) {
      const int n = nt * 16 + l15;
      const float bkv = bk[n];
      #pragma unroll
      for (int mt = 0; mt < 2; ++mt) {
        #pragma unroll
        for (int r = 0; r < 4; ++r) {
          const int crow = (wave * 2 + mt) * 16 + quad * 4 + r;
          const float v = acc[mt][nt][r] + bkv;
          const unsigned short hb = f2bf(v);
          Khi[crow * KP + n] = hb;
          Klo[crow * KP + n] = f2bf(v - bf2f(hb));
        }
      }
    }
  }
  __syncthreads();

  // ---------------- Phase B: S = Q @ K^T ----------------
  {
    // Q fragments for this wave's query tile (registers, all 4 ksteps)
    bf16x8 qhi[4], qlo[4];
    #pragma unroll
    for (int k4 = 0; k4 < 4; ++k4) {
      const float* src = &query[((size_t)b * NQ + wave * 16 + l15) * EE + k4 * 32 + quad * 8];
      const float4 x0 = *(const float4*)&src[0];
      const float4 x1 = *(const float4*)&src[4];
      float xv[8] = {x0.x, x0.y, x0.z, x0.w, x1.x, x1.y, x1.z, x1.w};
      u16x8 h, l;
      #pragma unroll
      for (int j = 0; j < 8; ++j) {
        unsigned short hb = f2bf(xv[j]);
        h[j] = hb;
        l[j] = f2bf(xv[j] - bf2f(hb));
      }
      qhi[k4] = __builtin_bit_cast(bf16x8, h);
      qlo[k4] = __builtin_bit_cast(bf16x8, l);
    }

    f32x4 acc[8];
    #pragma unroll
    for (int nt = 0; nt < 8; ++nt) acc[nt] = (f32x4){0.f, 0.f, 0.f, 0.f};

    #pragma unroll
    for (int k4 = 0; k4 < 4; ++k4) {
      const int k0 = k4 * 32 + quad * 8;
      #pragma unroll
      for (int nt = 0; nt < 8; ++nt) {
        const int crow = nt * 16 + l15;
        const bf16x8 khf = __builtin_bit_cast(bf16x8, *(const u16x8*)&Khi[crow * KP + k0]);
        const bf16x8 klf = __builtin_bit_cast(bf16x8, *(const u16x8*)&Klo[crow * KP + k0]);
        acc[nt] = __builtin_amdgcn_mfma_f32_16x16x32_bf16(qhi[k4], khf, acc[nt], 0, 0, 0);
        acc[nt] = __builtin_amdgcn_mfma_f32_16x16x32_bf16(qhi[k4], klf, acc[nt], 0, 0, 0);
        acc[nt] = __builtin_amdgcn_mfma_f32_16x16x32_bf16(qlo[k4], khf, acc[nt], 0, 0, 0);
      }
    }

    // epilogue: tanh*10, mask, store, column sums
    #pragma unroll
    for (int nt = 0; nt < 8; ++nt) {
      const int jloc  = nt * 16 + l15;
      const int jglob = ch * 128 + jloc;
      const bool jok  = (jglob < NCC);
      float s4 = 0.f;
      #pragma unroll
      for (int r = 0; r < 4; ++r) {
        const int q = wave * 16 + quad * 4 + r;
        float v = tanhf(acc[nt][r] * 0.25f) * 10.f;
        if (jok) {
          if (mask[((size_t)b * NQ + q) * (NCC + 1) + 1 + jglob]) v = -INFINITY;
          compat_out[((size_t)b * NQ + q) * NCC + jglob] = v;
        }
        s4 += v;
      }
      // reduce across the 4 row-groups (quad) -> full 16-query partial per wave
      s4 += __shfl_xor(s4, 16);
      s4 += __shfl_xor(s4, 32);
      if (lane < 16 && jok) atomicAdd(&colsum[jloc], s4);
    }
  }
  __syncthreads();

  if (tid < 128) {
    const int jglob = ch * 128 + tid;
    if (jglob < NCC)
      compts[(size_t)b * 1024 + jglob] = colsum[tid] * (1.0f / (float)NQ);
  }
}

// ---------------------------------------------------------------------------
// Kernel 3: per-batch argmax over compts with cluster masking.
// ---------------------------------------------------------------------------
__global__ __launch_bounds__(256) void argmax_kernel(
    const float* __restrict__ compts,
    const unsigned char* __restrict__ clusters,
    const int* __restrict__ depot_id,
    float* __restrict__ out)
{
  __shared__ float redv[256];
  __shared__ int   redi[256];
  const int b   = blockIdx.x;
  const int tid = threadIdx.x;
  const int dep = depot_id[0];
  float bestv = -INFINITY;
  int   besti = 0x7fffffff;
  for (int j = tid; j < NCC; j += 256) {
    float t = compts[(size_t)b * 1024 + j];
    if (clusters[((size_t)b * DD + dep) * NCC + j]) t = -INFINITY;
    if (t > bestv || (t == bestv && j < besti)) { bestv = t; besti = j; }
  }
  redv[tid] = bestv; redi[tid] = besti;
  __syncthreads();
  if (tid == 0) {
    float bv = redv[0]; int bi = redi[0];
    for (int t = 1; t < 256; ++t) {
      if (redv[t] > bv || (redv[t] == bv && redi[t] < bi)) {
        bv = redv[t]; bi = redi[t];
      }
    }
    out[b] = (float)bi;
  }
}

// ---------------------------------------------------------------------------
extern "C" void kernel_launch(void* const* d_in, const int* in_sizes, int n_in,
                              void* d_out, int out_size, void* d_ws, size_t ws_size,
                              hipStream_t stream) {
  const float* hin      = (const float*)d_in[0];
  const float* cin      = (const float*)d_in[1];
  const unsigned char* mask     = (const unsigned char*)d_in[2];
  const unsigned char* clusters = (const unsigned char*)d_in[3];
  const int*   depot    = (const int*)d_in[4];
  const float* gWq = (const float*)d_in[5];
  const float* gbq = (const float*)d_in[6];
  const float* gWk = (const float*)d_in[7];
  const float* gbk = (const float*)d_in[8];
  const float* gWv = (const float*)d_in[9];
  const float* gbv = (const float*)d_in[10];
  const float* gWo = (const float*)d_in[11];
  const float* gbo = (const float*)d_in[12];
  const float* Wq  = (const float*)d_in[13];
  const float* bq  = (const float*)d_in[14];
  const float* Wk  = (const float*)d_in[15];
  const float* bk  = (const float*)d_in[16];
  float* out   = (float*)d_out;
  float* compat_out = out + NB;

  // ws layout: query f32 (16 MiB) | wkt_hi (32 KiB) | wkt_lo (32 KiB) | compts (2 MiB)
  float*          query  = (float*)d_ws;
  unsigned short* wkt_hi = (unsigned short*)((char*)d_ws + (size_t)NB * NQ * EE * 4);
  unsigned short* wkt_lo = wkt_hi + EE * EE;
  float*          compts = (float*)(wkt_lo + EE * EE);

  gat_query_kernel<<<NB, 512, 0, stream>>>(hin, gWq, gbq, gWk, gbk, gWv, gbv,
                                           gWo, gbo, Wq, bq, query);
  wkt_kernel<<<64, 256, 0, stream>>>(Wk, wkt_hi, wkt_lo);
  compat_mfma_kernel<<<dim3(8, NB), 256, 0, stream>>>(
      cin, query, mask, wkt_hi, wkt_lo, bk, compat_out, compts);
  argmax_kernel<<<NB, 256, 0, stream>>>(compts, clusters, depot, out);
}